// Round 5
// baseline (998.535 us; speedup 1.0000x reference)
//
#include <hip/hip_runtime.h>
#include <math.h>

static __device__ __forceinline__ float silu_f(float v){ return v/(1.0f+expf(-v)); }
static __device__ __forceinline__ unsigned short f2bf(float f){
  unsigned int u=__float_as_uint(f);
  unsigned int r=(u + 0x7fffu + ((u>>16)&1u))>>16;
  return (unsigned short)r;
}
static __device__ __forceinline__ void bf2f(unsigned int u, float& a, float& b){
  a=__uint_as_float(u<<16); b=__uint_as_float(u & 0xffff0000u);
}

// ---------------- CSR build ----------------
__global__ void k_hist(const int* __restrict__ dst, int* __restrict__ cnt, int E){
  int e = blockIdx.x*256+threadIdx.x;
  if(e<E) atomicAdd(&cnt[dst[e]],1);
}
__global__ void k_dinv(const int* __restrict__ cnt, float* __restrict__ dinv, int n){
  int i = blockIdx.x*256+threadIdx.x;
  if(i<n) dinv[i]=rsqrtf((float)(cnt[i]+1));
}
__global__ void k_scan1(const int* __restrict__ cnt, int* __restrict__ rp, int* __restrict__ bs, int n){
  __shared__ int sh[256];
  int tid=threadIdx.x;
  int base = blockIdx.x*1024 + tid*4;
  int v0=0,v1=0,v2=0,v3=0;
  if(base+0<n)v0=cnt[base+0];
  if(base+1<n)v1=cnt[base+1];
  if(base+2<n)v2=cnt[base+2];
  if(base+3<n)v3=cnt[base+3];
  int s=v0+v1+v2+v3;
  sh[tid]=s; __syncthreads();
  for(int off=1;off<256;off<<=1){
    int t = (tid>=off)? sh[tid-off] : 0;
    __syncthreads();
    sh[tid]+=t;
    __syncthreads();
  }
  int run = sh[tid]-s;
  if(tid==255) bs[blockIdx.x]=sh[255];
  if(base+0<n){rp[base+0]=run; run+=v0;}
  if(base+1<n){rp[base+1]=run; run+=v1;}
  if(base+2<n){rp[base+2]=run; run+=v2;}
  if(base+3<n){rp[base+3]=run; run+=v3;}
}
// one-block parallel exclusive scan over per-block sums (nb <= 256)
__global__ void k_scan2(int* bs, int nb, int* rp, int n){
  __shared__ int sh[256];
  int tid=threadIdx.x;
  int v = (tid<nb)? bs[tid] : 0;
  sh[tid]=v; __syncthreads();
  for(int off=1;off<256;off<<=1){
    int t=(tid>=off)?sh[tid-off]:0;
    __syncthreads();
    sh[tid]+=t;
    __syncthreads();
  }
  if(tid<nb) bs[tid]=sh[tid]-v;
  if(tid==255) rp[n]=sh[255];
}
__global__ void k_scan3(int* rp, const int* __restrict__ bs, int n){
  int i = blockIdx.x*256+threadIdx.x;
  if(i<n) rp[i]+=bs[i>>10];
}
__global__ void k_fill(const int* __restrict__ src, const int* __restrict__ dst, int* cur,
                       const int* __restrict__ rp, int* __restrict__ csr, int E){
  int e = blockIdx.x*256+threadIdx.x;
  if(e<E){ int d=dst[e]; int p=atomicAdd(&cur[d],1); csr[rp[d]+p]=src[e]; }
}

// ---------------- electronegativity embedding: LDS-tiled GEMM + fused L2-norm ----------------
// fo = x[64-row tile] @ W (64x64) + b; out = ae[row] * fo/max(||fo||,1e-12), bf16.
__global__ __launch_bounds__(256) void k_en(const float* __restrict__ x, const float* __restrict__ W,
    const float* __restrict__ b, const float* __restrict__ ae, unsigned short* __restrict__ out, int Nn){
  __shared__ float As[64][68];   // x tile transposed: As[k][row]
  __shared__ float Bs[64][68];   // W: Bs[k][col]
  int bm = blockIdx.x*64;
  int tid = threadIdx.x;
  int ty = tid/16, tx = tid%16;
  #pragma unroll
  for(int i=0;i<16;i++){
    int idx=i*256+tid;
    int r=idx>>6, c=idx&63;
    Bs[r][c] = W[idx];
    As[c][r] = (bm+r<Nn) ? x[(size_t)(bm+r)*64 + c] : 0.0f;
  }
  __syncthreads();
  float acc[4][4]={{0}};
  #pragma unroll
  for(int k=0;k<64;k++){
    float a0=As[k][ty*4+0],a1=As[k][ty*4+1],a2=As[k][ty*4+2],a3=As[k][ty*4+3];
    float b0=Bs[k][tx*4+0],b1=Bs[k][tx*4+1],b2=Bs[k][tx*4+2],b3=Bs[k][tx*4+3];
    acc[0][0]+=a0*b0; acc[0][1]+=a0*b1; acc[0][2]+=a0*b2; acc[0][3]+=a0*b3;
    acc[1][0]+=a1*b0; acc[1][1]+=a1*b1; acc[1][2]+=a1*b2; acc[1][3]+=a1*b3;
    acc[2][0]+=a2*b0; acc[2][1]+=a2*b1; acc[2][2]+=a2*b2; acc[2][3]+=a2*b3;
    acc[3][0]+=a3*b0; acc[3][1]+=a3*b1; acc[3][2]+=a3*b2; acc[3][3]+=a3*b3;
  }
  float bb0=b[tx*4+0], bb1=b[tx*4+1], bb2=b[tx*4+2], bb3=b[tx*4+3];
  #pragma unroll
  for(int i=0;i<4;i++){
    int row = bm+ty*4+i;
    float v0=acc[i][0]+bb0, v1=acc[i][1]+bb1, v2=acc[i][2]+bb2, v3=acc[i][3]+bb3;
    float ss = v0*v0+v1*v1+v2*v2+v3*v3;
    // reduce across the 16-lane segment owning this row (tx = lane&15)
    ss += __shfl_xor(ss,1); ss += __shfl_xor(ss,2);
    ss += __shfl_xor(ss,4); ss += __shfl_xor(ss,8);
    if(row<Nn){
      float scale = ae[row] / fmaxf(sqrtf(ss), 1e-12f);
      ushort4 o;
      o.x=f2bf(v0*scale); o.y=f2bf(v1*scale); o.z=f2bf(v2*scale); o.w=f2bf(v3*scale);
      *(ushort4*)&out[(size_t)row*64 + tx*4] = o;
    }
  }
}

// ---------------- GCN propagate (A-hat @ h), bf16 input, fp32 out ------------
// FB = groups of 8 bf16 per row (F = FB*8). FB threads cooperate on one node.
template<int FB>
__global__ __launch_bounds__(256) void k_prop_bf(const unsigned short* __restrict__ h, float* __restrict__ out,
                       const int* __restrict__ rp, const int* __restrict__ csr,
                       const float* __restrict__ dinv, int Nn){
  int t = blockIdx.x*256+threadIdx.x;
  int n = t/FB;
  if(n>=Nn) return;
  int g = (t%FB)*8;
  const int F = FB*8;
  float dn = dinv[n];
  float a0,a1,a2,a3,a4,a5,a6,a7;
  {
    uint4 u = *(const uint4*)&h[(size_t)n*F+g];
    bf2f(u.x,a0,a1); bf2f(u.y,a2,a3); bf2f(u.z,a4,a5); bf2f(u.w,a6,a7);
    a0*=dn;a1*=dn;a2*=dn;a3*=dn;a4*=dn;a5*=dn;a6*=dn;a7*=dn;
  }
  int e=rp[n], e1=rp[n+1];
  for(; e+1<e1; e+=2){
    int s0=csr[e], s1=csr[e+1];
    float w0=dinv[s0], w1=dinv[s1];
    uint4 u0 = *(const uint4*)&h[(size_t)s0*F+g];
    uint4 u1 = *(const uint4*)&h[(size_t)s1*F+g];
    float b0,b1,b2,b3,b4,b5,b6,b7;
    bf2f(u0.x,b0,b1); bf2f(u0.y,b2,b3); bf2f(u0.z,b4,b5); bf2f(u0.w,b6,b7);
    a0+=b0*w0; a1+=b1*w0; a2+=b2*w0; a3+=b3*w0;
    a4+=b4*w0; a5+=b5*w0; a6+=b6*w0; a7+=b7*w0;
    bf2f(u1.x,b0,b1); bf2f(u1.y,b2,b3); bf2f(u1.z,b4,b5); bf2f(u1.w,b6,b7);
    a0+=b0*w1; a1+=b1*w1; a2+=b2*w1; a3+=b3*w1;
    a4+=b4*w1; a5+=b5*w1; a6+=b6*w1; a7+=b7*w1;
  }
  if(e<e1){
    int s=csr[e]; float w=dinv[s];
    uint4 u = *(const uint4*)&h[(size_t)s*F+g];
    float b0,b1,b2,b3,b4,b5,b6,b7;
    bf2f(u.x,b0,b1); bf2f(u.y,b2,b3); bf2f(u.z,b4,b5); bf2f(u.w,b6,b7);
    a0+=b0*w; a1+=b1*w; a2+=b2*w; a3+=b3*w;
    a4+=b4*w; a5+=b5*w; a6+=b6*w; a7+=b7*w;
  }
  float4 o0; o0.x=a0*dn; o0.y=a1*dn; o0.z=a2*dn; o0.w=a3*dn;
  float4 o1; o1.x=a4*dn; o1.y=a5*dn; o1.z=a6*dn; o1.w=a7*dn;
  *(float4*)&out[(size_t)n*F+g]   = o0;
  *(float4*)&out[(size_t)n*F+g+4] = o1;
}

// ---------------- generic fp32 GEMM + optional bf16 epilogue output ----------
__global__ __launch_bounds__(256) void k_gemm(const float* __restrict__ A, const float* __restrict__ W,
    const float* __restrict__ bias, float* __restrict__ C, unsigned short* __restrict__ Cbf,
    int M, int K, int D, int ldc, int act){
  __shared__ float As[32][68];
  __shared__ float Bs[32][68];
  int bm = blockIdx.x*64, bn = blockIdx.y*64;
  int tid = threadIdx.x;
  int ty = tid/16, tx = tid%16;
  float acc[4][4] = {{0}};
  for(int k0=0;k0<K;k0+=32){
    #pragma unroll
    for(int i=0;i<8;i++){
      int idx = i*256+tid;
      int r = idx>>5, c = idx&31;
      As[c][r] = (bm+r<M) ? A[(size_t)(bm+r)*K + k0+c] : 0.0f;
    }
    #pragma unroll
    for(int i=0;i<8;i++){
      int idx = i*256+tid;
      int r = idx>>6, c = idx&63;
      Bs[r][c] = W[(size_t)(k0+r)*D + bn+c];
    }
    __syncthreads();
    #pragma unroll
    for(int k=0;k<32;k++){
      float a0=As[k][ty*4+0],a1=As[k][ty*4+1],a2=As[k][ty*4+2],a3=As[k][ty*4+3];
      float b0=Bs[k][tx*4+0],b1=Bs[k][tx*4+1],b2=Bs[k][tx*4+2],b3=Bs[k][tx*4+3];
      acc[0][0]+=a0*b0; acc[0][1]+=a0*b1; acc[0][2]+=a0*b2; acc[0][3]+=a0*b3;
      acc[1][0]+=a1*b0; acc[1][1]+=a1*b1; acc[1][2]+=a1*b2; acc[1][3]+=a1*b3;
      acc[2][0]+=a2*b0; acc[2][1]+=a2*b1; acc[2][2]+=a2*b2; acc[2][3]+=a2*b3;
      acc[3][0]+=a3*b0; acc[3][1]+=a3*b1; acc[3][2]+=a3*b2; acc[3][3]+=a3*b3;
    }
    __syncthreads();
  }
  #pragma unroll
  for(int i=0;i<4;i++){
    int r = bm+ty*4+i;
    if(r<M){
      #pragma unroll
      for(int j=0;j<4;j++){
        int c = bn+tx*4+j;
        float v = acc[i][j] + bias[c];
        if(act) v = silu_f(v);
        if(C)   C[(size_t)r*ldc + c] = v;
        if(Cbf) Cbf[(size_t)r*ldc + c] = f2bf(v);
      }
    }
  }
}

// ---------------- BatchNorm stats: parallel, vectorized, block-reduced ----------------
__global__ __launch_bounds__(256) void k_bnstats(const float* __restrict__ A, float* __restrict__ sums,
                                                 int rows, int rpb){
  __shared__ float sh1[4][128];
  __shared__ float sh2[4][128];
  int tid=threadIdx.x;
  int sub=tid>>5;
  int cg=tid&31;
  int r0=blockIdx.x*rpb, r1=min(r0+rpb,rows);
  float s1x=0,s1y=0,s1z=0,s1w=0, s2x=0,s2y=0,s2z=0,s2w=0;
  for(int r=r0+sub; r<r1; r+=8){
    float4 v = *(const float4*)&A[(size_t)r*128 + cg*4];
    s1x+=v.x; s2x+=v.x*v.x;
    s1y+=v.y; s2y+=v.y*v.y;
    s1z+=v.z; s2z+=v.z*v.z;
    s1w+=v.w; s2w+=v.w*v.w;
  }
  s1x+=__shfl_xor(s1x,32); s1y+=__shfl_xor(s1y,32); s1z+=__shfl_xor(s1z,32); s1w+=__shfl_xor(s1w,32);
  s2x+=__shfl_xor(s2x,32); s2y+=__shfl_xor(s2y,32); s2z+=__shfl_xor(s2z,32); s2w+=__shfl_xor(s2w,32);
  int wave=tid>>6, lane=tid&63;
  if(lane<32){
    sh1[wave][cg*4+0]=s1x; sh1[wave][cg*4+1]=s1y; sh1[wave][cg*4+2]=s1z; sh1[wave][cg*4+3]=s1w;
    sh2[wave][cg*4+0]=s2x; sh2[wave][cg*4+1]=s2y; sh2[wave][cg*4+2]=s2z; sh2[wave][cg*4+3]=s2w;
  }
  __syncthreads();
  if(tid<128){
    float p=sh1[0][tid]+sh1[1][tid]+sh1[2][tid]+sh1[3][tid];
    atomicAdd(&sums[tid],p);
  } else {
    int c=tid-128;
    float p=sh2[0][c]+sh2[1][c]+sh2[2][c]+sh2[3][c];
    atomicAdd(&sums[128+c],p);
  }
}
__global__ void k_bnfinal(const float* __restrict__ sums, const float* __restrict__ g,
                          const float* __restrict__ b, float* __restrict__ sc, int rows){
  int c = threadIdx.x;
  float mu = sums[c]/rows;
  float var = sums[128+c]/rows - mu*mu;
  float a = g[c]*rsqrtf(var+1e-5f);
  sc[c]=a; sc[128+c]=b[c]-mu*a;
}
// BN+silu, fp32 in -> bf16 out (node pipeline)
__global__ __launch_bounds__(256) void k_bnsilu_bf(const float* __restrict__ A, unsigned short* __restrict__ O,
                                                   const float* __restrict__ sc, int total4){
  int i = blockIdx.x*256+threadIdx.x;
  if(i<total4){
    int c4=(i&31)*4;
    float4 v = ((const float4*)A)[i];
    ushort4 o;
    o.x = f2bf(silu_f(v.x*sc[c4+0]+sc[128+c4+0]));
    o.y = f2bf(silu_f(v.y*sc[c4+1]+sc[128+c4+1]));
    o.z = f2bf(silu_f(v.z*sc[c4+2]+sc[128+c4+2]));
    o.w = f2bf(silu_f(v.w*sc[c4+3]+sc[128+c4+3]));
    *(ushort4*)&O[(size_t)i*4] = o;
  }
}
// BN+silu, fp32 in-place (mol branch)
__global__ __launch_bounds__(256) void k_bnsilu(float* __restrict__ A, const float* __restrict__ sc, int total4){
  int i = blockIdx.x*256+threadIdx.x;
  if(i<total4){
    int c4=(i&31)*4;
    float4 v = ((const float4*)A)[i];
    v.x = silu_f(v.x*sc[c4+0]+sc[128+c4+0]);
    v.y = silu_f(v.y*sc[c4+1]+sc[128+c4+1]);
    v.z = silu_f(v.z*sc[c4+2]+sc[128+c4+2]);
    v.w = silu_f(v.w*sc[c4+3]+sc[128+c4+3]);
    ((float4*)A)[i] = v;
  }
}

// ---------------- global_add_pool (batch sorted -> range sum per graph) ----------------
__global__ __launch_bounds__(256) void k_pool(const float* __restrict__ h, const int* __restrict__ batch,
                       float* __restrict__ P, int Nn, int G){
  int t = blockIdx.x*256+threadIdx.x;
  int g = t>>5;
  if(g>=G) return;
  int c4=(t&31)*4;
  int lo=0, hi=Nn;
  while(lo<hi){ int m=(lo+hi)>>1; if(batch[m]<g) lo=m+1; else hi=m; }
  int s=lo;
  lo=0; hi=Nn;
  while(lo<hi){ int m=(lo+hi)>>1; if(batch[m]<=g) lo=m+1; else hi=m; }
  int e=lo;
  float ax=0,ay=0,az=0,aw=0;
  for(int r=s;r<e;r++){
    float4 v = *(const float4*)&h[(size_t)r*128+c4];
    ax+=v.x; ay+=v.y; az+=v.z; aw+=v.w;
  }
  float4 o; o.x=ax;o.y=ay;o.z=az;o.w=aw;
  *(float4*)&P[(size_t)g*256+c4] = o;
}

// ---------------- final dot: out[g] = z2[g]@fW3 + fb3 ----------------
__global__ void k_dot(const float* __restrict__ z, const float* __restrict__ w,
                      const float* __restrict__ b, float* __restrict__ out){
  int g = blockIdx.x; int lane = threadIdx.x; // 64
  float p = z[(size_t)g*64+lane]*w[lane];
  #pragma unroll
  for(int off=32;off;off>>=1) p += __shfl_xor(p,off);
  if(lane==0) out[g] = p + b[0];
}

extern "C" void kernel_launch(void* const* d_in, const int* in_sizes, int n_in,
                              void* d_out, int out_size, void* d_ws, size_t ws_size,
                              hipStream_t stream){
  const float* x       =(const float*)d_in[0];
  const float* atom_ens=(const float*)d_in[1];
  const float* mol     =(const float*)d_in[2];
  const int*   eidx    =(const int*)d_in[3];
  const int*   batch   =(const int*)d_in[4];
  const float* W_en=(const float*)d_in[5];  const float* b_en=(const float*)d_in[6];
  const float* gW0=(const float*)d_in[7];   const float* gb0=(const float*)d_in[8];
  const float* gW1=(const float*)d_in[9];   const float* gb1=(const float*)d_in[10];
  const float* gW2=(const float*)d_in[11];  const float* gb2=(const float*)d_in[12];
  const float* bn_gc_g=(const float*)d_in[13]; const float* bn_gc_b=(const float*)d_in[14];
  const float* mW0=(const float*)d_in[15];  const float* mb0=(const float*)d_in[16];
  const float* mW1=(const float*)d_in[17];  const float* mb1=(const float*)d_in[18];
  const float* mW2=(const float*)d_in[19];  const float* mb2=(const float*)d_in[20];
  const float* bn_m_g=(const float*)d_in[21]; const float* bn_m_b=(const float*)d_in[22];
  const float* fW0=(const float*)d_in[23];  const float* fb0=(const float*)d_in[24];
  const float* fW1=(const float*)d_in[25];  const float* fb1=(const float*)d_in[26];
  const float* fW2=(const float*)d_in[27];  const float* fb2=(const float*)d_in[28];
  const float* fW3=(const float*)d_in[29];  const float* fb3=(const float*)d_in[30];

  const int N = in_sizes[1];
  const int E = in_sizes[3]/2;
  const int G = in_sizes[2]/128;
  const int* esrc = eidx;
  const int* edst = eidx+E;

  char* ws=(char*)d_ws;
  size_t o=0;
  float* A=(float*)(ws+o);    o += (size_t)N*128*4;
  float* B=(float*)(ws+o);    o += (size_t)N*128*4;
  unsigned short* Abf=(unsigned short*)(ws+o); o += (size_t)N*128*2;
  float* dinv=(float*)(ws+o); o += (size_t)N*4;
  int* cnt=(int*)(ws+o);      o += (size_t)N*4;
  int* rp=(int*)(ws+o);       o += (size_t)(N+1)*4; o=(o+255)&~(size_t)255;
  int* bs=(int*)(ws+o);       o += 4096;
  float* sums=(float*)(ws+o); o += 1024;
  float* sc=(float*)(ws+o);   o += 1024;
  int* csr=(int*)(ws+o);      o += (size_t)E*4;
  if(o > ws_size) return;

  unsigned short* enbf = (unsigned short*)A;  // N x 64 bf16, dead once gemm0 writes A
  float* P  = B;               // G x 256 (concat buffer; B free after pool input A)
  float* Q  = P + (size_t)G*256;
  float* MB0= Q + (size_t)G*256; // G x 128
  float* MB1= MB0 + (size_t)G*128;
  float* Z2 = MB1 + (size_t)G*128; // G x 64

  dim3 blk256(256);
  int nb = (N+1023)/1024;

  // --- CSR build ---
  hipMemsetAsync(cnt, 0, (size_t)N*4, stream);
  k_hist<<<dim3((E+255)/256), blk256, 0, stream>>>(edst, cnt, E);
  k_dinv<<<dim3((N+255)/256), blk256, 0, stream>>>(cnt, dinv, N);
  k_scan1<<<dim3(nb), blk256, 0, stream>>>(cnt, rp, bs, N);
  k_scan2<<<dim3(1), blk256, 0, stream>>>(bs, nb, rp, N);
  k_scan3<<<dim3((N+255)/256), blk256, 0, stream>>>(rp, bs, N);
  hipMemsetAsync(cnt, 0, (size_t)N*4, stream);
  k_fill<<<dim3((E+255)/256), blk256, 0, stream>>>(esrc, edst, cnt, rp, csr, E);

  // --- en embedding -> enbf (N x 64 bf16, in A's space) ---
  k_en<<<dim3((N+63)/64), blk256, 0, stream>>>(x, W_en, b_en, atom_ens, enbf, N);

  // --- layer 0: prop(en bf16) -> B (64 fp32), @gW0+gb0 -> A (128 fp32), BN, silu->bf16 ---
  k_prop_bf<8><<<dim3((N*8+255)/256), blk256, 0, stream>>>(enbf, B, rp, csr, dinv, N);
  k_gemm<<<dim3((N+63)/64, 2), blk256, 0, stream>>>(B, gW0, gb0, A, (unsigned short*)nullptr, N, 64, 128, 128, 0);
  {
    int nblk=512, rpb=(N+nblk-1)/nblk;
    hipMemsetAsync(sums, 0, 1024, stream);
    k_bnstats<<<dim3(nblk), blk256, 0, stream>>>(A, sums, N, rpb);
    k_bnfinal<<<dim3(1), dim3(128), 0, stream>>>(sums, bn_gc_g, bn_gc_b, sc, N);
    k_bnsilu_bf<<<dim3((N*32+255)/256), blk256, 0, stream>>>(A, Abf, sc, N*32);
  }

  // --- layer 1: prop(Abf) -> B, gemm+silu -> Abf (bf16 only) ---
  k_prop_bf<16><<<dim3((N*16+255)/256), blk256, 0, stream>>>(Abf, B, rp, csr, dinv, N);
  k_gemm<<<dim3((N+63)/64, 2), blk256, 0, stream>>>(B, gW1, gb1, (float*)nullptr, Abf, N, 128, 128, 128, 1);

  // --- layer 2: prop(Abf) -> B, gemm+silu -> A (fp32 for pool) ---
  k_prop_bf<16><<<dim3((N*16+255)/256), blk256, 0, stream>>>(Abf, B, rp, csr, dinv, N);
  k_gemm<<<dim3((N+63)/64, 2), blk256, 0, stream>>>(B, gW2, gb2, A, (unsigned short*)nullptr, N, 128, 128, 128, 1);

  // --- pool into P[:, :128] ---
  k_pool<<<dim3((G*32+255)/256), blk256, 0, stream>>>(A, batch, P, N, G);

  // --- mol branch -> P[:, 128:256] ---
  k_gemm<<<dim3((G+63)/64, 2), blk256, 0, stream>>>(mol, mW0, mb0, MB0, (unsigned short*)nullptr, G, 128, 128, 128, 0);
  {
    int nblk=64, rpb=(G+nblk-1)/nblk;
    hipMemsetAsync(sums, 0, 1024, stream);
    k_bnstats<<<dim3(nblk), blk256, 0, stream>>>(MB0, sums, G, rpb);
    k_bnfinal<<<dim3(1), dim3(128), 0, stream>>>(sums, bn_m_g, bn_m_b, sc, G);
    k_bnsilu<<<dim3((G*32+255)/256), blk256, 0, stream>>>(MB0, sc, G*32);
  }
  k_gemm<<<dim3((G+63)/64, 2), blk256, 0, stream>>>(MB0, mW1, mb1, MB1, (unsigned short*)nullptr, G, 128, 128, 128, 1);
  k_gemm<<<dim3((G+63)/64, 2), blk256, 0, stream>>>(MB1, mW2, mb2, P+128, (unsigned short*)nullptr, G, 128, 128, 256, 1);

  // --- fused head ---
  k_gemm<<<dim3((G+63)/64, 4), blk256, 0, stream>>>(P, fW0, fb0, Q, (unsigned short*)nullptr, G, 256, 256, 256, 1);
  k_gemm<<<dim3((G+63)/64, 4), blk256, 0, stream>>>(Q, fW1, fb1, P, (unsigned short*)nullptr, G, 256, 256, 256, 1);
  k_gemm<<<dim3((G+63)/64, 1), blk256, 0, stream>>>(P, fW2, fb2, Z2, (unsigned short*)nullptr, G, 256, 64, 64, 1);
  k_dot<<<dim3(G), dim3(64), 0, stream>>>(Z2, fW3, fb3, (float*)d_out);
}

// Round 6
// 895.470 us; speedup vs baseline: 1.1151x; 1.1151x over previous
//
#include <hip/hip_runtime.h>
#include <math.h>

static __device__ __forceinline__ float silu_f(float v){ return v/(1.0f+expf(-v)); }
static __device__ __forceinline__ unsigned short f2bf(float f){
  unsigned int u=__float_as_uint(f);
  unsigned int r=(u + 0x7fffu + ((u>>16)&1u))>>16;
  return (unsigned short)r;
}
static __device__ __forceinline__ void bf2f(unsigned int u, float& a, float& b){
  a=__uint_as_float(u<<16); b=__uint_as_float(u & 0xffff0000u);
}

// ---------------- CSR build ----------------
__global__ void k_hist(const int* __restrict__ dst, int* __restrict__ cnt, int E){
  int e = blockIdx.x*256+threadIdx.x;
  if(e<E) atomicAdd(&cnt[dst[e]],1);
}
__global__ void k_dinv(const int* __restrict__ cnt, float* __restrict__ dinv, int n){
  int i = blockIdx.x*256+threadIdx.x;
  if(i<n) dinv[i]=rsqrtf((float)(cnt[i]+1));
}
__global__ void k_scan1(const int* __restrict__ cnt, int* __restrict__ rp, int* __restrict__ bs, int n){
  __shared__ int sh[256];
  int tid=threadIdx.x;
  int base = blockIdx.x*1024 + tid*4;
  int v0=0,v1=0,v2=0,v3=0;
  if(base+0<n)v0=cnt[base+0];
  if(base+1<n)v1=cnt[base+1];
  if(base+2<n)v2=cnt[base+2];
  if(base+3<n)v3=cnt[base+3];
  int s=v0+v1+v2+v3;
  sh[tid]=s; __syncthreads();
  for(int off=1;off<256;off<<=1){
    int t = (tid>=off)? sh[tid-off] : 0;
    __syncthreads();
    sh[tid]+=t;
    __syncthreads();
  }
  int run = sh[tid]-s;
  if(tid==255) bs[blockIdx.x]=sh[255];
  if(base+0<n){rp[base+0]=run; run+=v0;}
  if(base+1<n){rp[base+1]=run; run+=v1;}
  if(base+2<n){rp[base+2]=run; run+=v2;}
  if(base+3<n){rp[base+3]=run; run+=v3;}
}
// one-block parallel exclusive scan over per-block sums (nb <= 256)
__global__ void k_scan2(int* bs, int nb, int* rp, int n){
  __shared__ int sh[256];
  int tid=threadIdx.x;
  int v = (tid<nb)? bs[tid] : 0;
  sh[tid]=v; __syncthreads();
  for(int off=1;off<256;off<<=1){
    int t=(tid>=off)?sh[tid-off]:0;
    __syncthreads();
    sh[tid]+=t;
    __syncthreads();
  }
  if(tid<nb) bs[tid]=sh[tid]-v;
  if(tid==255) rp[n]=sh[255];
}
__global__ void k_scan3(int* rp, const int* __restrict__ bs, int n){
  int i = blockIdx.x*256+threadIdx.x;
  if(i<n) rp[i]+=bs[i>>10];
}
__global__ void k_fill(const int* __restrict__ src, const int* __restrict__ dst, int* cur,
                       const int* __restrict__ rp, int* __restrict__ csr, int E){
  int e = blockIdx.x*256+threadIdx.x;
  if(e<E){ int d=dst[e]; int p=atomicAdd(&cur[d],1); csr[rp[d]+p]=src[e]; }
}

// ---------------- electronegativity embedding: k_gemm-structured + fused L2-norm ----------------
// fo = x[64-row tile] @ W_en (64x64) + b; out = ae[row] * fo/max(||fo||,1e-12), bf16.
// Mirrors k_gemm's BK=32 chunked loop exactly (proven VGPR/occupancy profile).
__global__ __launch_bounds__(256) void k_en(const float* __restrict__ x, const float* __restrict__ W,
    const float* __restrict__ b, const float* __restrict__ ae, unsigned short* __restrict__ out, int Nn){
  __shared__ float As[32][68];
  __shared__ float Bs[32][68];
  int bm = blockIdx.x*64;
  int tid = threadIdx.x;
  int ty = tid/16, tx = tid%16;
  float acc[4][4] = {{0}};
  for(int k0=0;k0<64;k0+=32){
    #pragma unroll
    for(int i=0;i<8;i++){
      int idx = i*256+tid;
      int r = idx>>5, c = idx&31;
      As[c][r] = (bm+r<Nn) ? x[(size_t)(bm+r)*64 + k0+c] : 0.0f;
    }
    #pragma unroll
    for(int i=0;i<8;i++){
      int idx = i*256+tid;
      int r = idx>>6, c = idx&63;
      Bs[r][c] = W[(size_t)(k0+r)*64 + c];
    }
    __syncthreads();
    #pragma unroll
    for(int k=0;k<32;k++){
      float a0=As[k][ty*4+0],a1=As[k][ty*4+1],a2=As[k][ty*4+2],a3=As[k][ty*4+3];
      float b0=Bs[k][tx*4+0],b1=Bs[k][tx*4+1],b2=Bs[k][tx*4+2],b3=Bs[k][tx*4+3];
      acc[0][0]+=a0*b0; acc[0][1]+=a0*b1; acc[0][2]+=a0*b2; acc[0][3]+=a0*b3;
      acc[1][0]+=a1*b0; acc[1][1]+=a1*b1; acc[1][2]+=a1*b2; acc[1][3]+=a1*b3;
      acc[2][0]+=a2*b0; acc[2][1]+=a2*b1; acc[2][2]+=a2*b2; acc[2][3]+=a2*b3;
      acc[3][0]+=a3*b0; acc[3][1]+=a3*b1; acc[3][2]+=a3*b2; acc[3][3]+=a3*b3;
    }
    __syncthreads();
  }
  float bb0=b[tx*4+0], bb1=b[tx*4+1], bb2=b[tx*4+2], bb3=b[tx*4+3];
  #pragma unroll
  for(int i=0;i<4;i++){
    int row = bm+ty*4+i;
    float v0=acc[i][0]+bb0, v1=acc[i][1]+bb1, v2=acc[i][2]+bb2, v3=acc[i][3]+bb3;
    float ss = v0*v0+v1*v1+v2*v2+v3*v3;
    // reduce across the 16-lane segment owning this row (tx = lane&15)
    ss += __shfl_xor(ss,1); ss += __shfl_xor(ss,2);
    ss += __shfl_xor(ss,4); ss += __shfl_xor(ss,8);
    if(row<Nn){
      float scale = ae[row] / fmaxf(sqrtf(ss), 1e-12f);
      ushort4 o;
      o.x=f2bf(v0*scale); o.y=f2bf(v1*scale); o.z=f2bf(v2*scale); o.w=f2bf(v3*scale);
      *(ushort4*)&out[(size_t)row*64 + tx*4] = o;
    }
  }
}

// ---------------- GCN propagate (A-hat @ h), bf16 input, fp32 out ------------
// FB = groups of 8 bf16 per row (F = FB*8). FB threads cooperate on one node.
template<int FB>
__global__ __launch_bounds__(256) void k_prop_bf(const unsigned short* __restrict__ h, float* __restrict__ out,
                       const int* __restrict__ rp, const int* __restrict__ csr,
                       const float* __restrict__ dinv, int Nn){
  int t = blockIdx.x*256+threadIdx.x;
  int n = t/FB;
  if(n>=Nn) return;
  int g = (t%FB)*8;
  const int F = FB*8;
  float dn = dinv[n];
  float a0,a1,a2,a3,a4,a5,a6,a7;
  {
    uint4 u = *(const uint4*)&h[(size_t)n*F+g];
    bf2f(u.x,a0,a1); bf2f(u.y,a2,a3); bf2f(u.z,a4,a5); bf2f(u.w,a6,a7);
    a0*=dn;a1*=dn;a2*=dn;a3*=dn;a4*=dn;a5*=dn;a6*=dn;a7*=dn;
  }
  int e=rp[n], e1=rp[n+1];
  for(; e+1<e1; e+=2){
    int s0=csr[e], s1=csr[e+1];
    float w0=dinv[s0], w1=dinv[s1];
    uint4 u0 = *(const uint4*)&h[(size_t)s0*F+g];
    uint4 u1 = *(const uint4*)&h[(size_t)s1*F+g];
    float b0,b1,b2,b3,b4,b5,b6,b7;
    bf2f(u0.x,b0,b1); bf2f(u0.y,b2,b3); bf2f(u0.z,b4,b5); bf2f(u0.w,b6,b7);
    a0+=b0*w0; a1+=b1*w0; a2+=b2*w0; a3+=b3*w0;
    a4+=b4*w0; a5+=b5*w0; a6+=b6*w0; a7+=b7*w0;
    bf2f(u1.x,b0,b1); bf2f(u1.y,b2,b3); bf2f(u1.z,b4,b5); bf2f(u1.w,b6,b7);
    a0+=b0*w1; a1+=b1*w1; a2+=b2*w1; a3+=b3*w1;
    a4+=b4*w1; a5+=b5*w1; a6+=b6*w1; a7+=b7*w1;
  }
  if(e<e1){
    int s=csr[e]; float w=dinv[s];
    uint4 u = *(const uint4*)&h[(size_t)s*F+g];
    float b0,b1,b2,b3,b4,b5,b6,b7;
    bf2f(u.x,b0,b1); bf2f(u.y,b2,b3); bf2f(u.z,b4,b5); bf2f(u.w,b6,b7);
    a0+=b0*w; a1+=b1*w; a2+=b2*w; a3+=b3*w;
    a4+=b4*w; a5+=b5*w; a6+=b6*w; a7+=b7*w;
  }
  float4 o0; o0.x=a0*dn; o0.y=a1*dn; o0.z=a2*dn; o0.w=a3*dn;
  float4 o1; o1.x=a4*dn; o1.y=a5*dn; o1.z=a6*dn; o1.w=a7*dn;
  *(float4*)&out[(size_t)n*F+g]   = o0;
  *(float4*)&out[(size_t)n*F+g+4] = o1;
}

// ---------------- generic fp32 GEMM + optional bf16 epilogue output ----------
__global__ __launch_bounds__(256) void k_gemm(const float* __restrict__ A, const float* __restrict__ W,
    const float* __restrict__ bias, float* __restrict__ C, unsigned short* __restrict__ Cbf,
    int M, int K, int D, int ldc, int act){
  __shared__ float As[32][68];
  __shared__ float Bs[32][68];
  int bm = blockIdx.x*64, bn = blockIdx.y*64;
  int tid = threadIdx.x;
  int ty = tid/16, tx = tid%16;
  float acc[4][4] = {{0}};
  for(int k0=0;k0<K;k0+=32){
    #pragma unroll
    for(int i=0;i<8;i++){
      int idx = i*256+tid;
      int r = idx>>5, c = idx&31;
      As[c][r] = (bm+r<M) ? A[(size_t)(bm+r)*K + k0+c] : 0.0f;
    }
    #pragma unroll
    for(int i=0;i<8;i++){
      int idx = i*256+tid;
      int r = idx>>6, c = idx&63;
      Bs[r][c] = W[(size_t)(k0+r)*D + bn+c];
    }
    __syncthreads();
    #pragma unroll
    for(int k=0;k<32;k++){
      float a0=As[k][ty*4+0],a1=As[k][ty*4+1],a2=As[k][ty*4+2],a3=As[k][ty*4+3];
      float b0=Bs[k][tx*4+0],b1=Bs[k][tx*4+1],b2=Bs[k][tx*4+2],b3=Bs[k][tx*4+3];
      acc[0][0]+=a0*b0; acc[0][1]+=a0*b1; acc[0][2]+=a0*b2; acc[0][3]+=a0*b3;
      acc[1][0]+=a1*b0; acc[1][1]+=a1*b1; acc[1][2]+=a1*b2; acc[1][3]+=a1*b3;
      acc[2][0]+=a2*b0; acc[2][1]+=a2*b1; acc[2][2]+=a2*b2; acc[2][3]+=a2*b3;
      acc[3][0]+=a3*b0; acc[3][1]+=a3*b1; acc[3][2]+=a3*b2; acc[3][3]+=a3*b3;
    }
    __syncthreads();
  }
  #pragma unroll
  for(int i=0;i<4;i++){
    int r = bm+ty*4+i;
    if(r<M){
      #pragma unroll
      for(int j=0;j<4;j++){
        int c = bn+tx*4+j;
        float v = acc[i][j] + bias[c];
        if(act) v = silu_f(v);
        if(C)   C[(size_t)r*ldc + c] = v;
        if(Cbf) Cbf[(size_t)r*ldc + c] = f2bf(v);
      }
    }
  }
}

// ---------------- BatchNorm stats: parallel, vectorized, block-reduced ----------------
__global__ __launch_bounds__(256) void k_bnstats(const float* __restrict__ A, float* __restrict__ sums,
                                                 int rows, int rpb){
  __shared__ float sh1[4][128];
  __shared__ float sh2[4][128];
  int tid=threadIdx.x;
  int sub=tid>>5;
  int cg=tid&31;
  int r0=blockIdx.x*rpb, r1=min(r0+rpb,rows);
  float s1x=0,s1y=0,s1z=0,s1w=0, s2x=0,s2y=0,s2z=0,s2w=0;
  for(int r=r0+sub; r<r1; r+=8){
    float4 v = *(const float4*)&A[(size_t)r*128 + cg*4];
    s1x+=v.x; s2x+=v.x*v.x;
    s1y+=v.y; s2y+=v.y*v.y;
    s1z+=v.z; s2z+=v.z*v.z;
    s1w+=v.w; s2w+=v.w*v.w;
  }
  s1x+=__shfl_xor(s1x,32); s1y+=__shfl_xor(s1y,32); s1z+=__shfl_xor(s1z,32); s1w+=__shfl_xor(s1w,32);
  s2x+=__shfl_xor(s2x,32); s2y+=__shfl_xor(s2y,32); s2z+=__shfl_xor(s2z,32); s2w+=__shfl_xor(s2w,32);
  int wave=tid>>6, lane=tid&63;
  if(lane<32){
    sh1[wave][cg*4+0]=s1x; sh1[wave][cg*4+1]=s1y; sh1[wave][cg*4+2]=s1z; sh1[wave][cg*4+3]=s1w;
    sh2[wave][cg*4+0]=s2x; sh2[wave][cg*4+1]=s2y; sh2[wave][cg*4+2]=s2z; sh2[wave][cg*4+3]=s2w;
  }
  __syncthreads();
  if(tid<128){
    float p=sh1[0][tid]+sh1[1][tid]+sh1[2][tid]+sh1[3][tid];
    atomicAdd(&sums[tid],p);
  } else {
    int c=tid-128;
    float p=sh2[0][c]+sh2[1][c]+sh2[2][c]+sh2[3][c];
    atomicAdd(&sums[128+c],p);
  }
}
__global__ void k_bnfinal(const float* __restrict__ sums, const float* __restrict__ g,
                          const float* __restrict__ b, float* __restrict__ sc, int rows){
  int c = threadIdx.x;
  float mu = sums[c]/rows;
  float var = sums[128+c]/rows - mu*mu;
  float a = g[c]*rsqrtf(var+1e-5f);
  sc[c]=a; sc[128+c]=b[c]-mu*a;
}
// BN+silu, fp32 in -> bf16 out (node pipeline)
__global__ __launch_bounds__(256) void k_bnsilu_bf(const float* __restrict__ A, unsigned short* __restrict__ O,
                                                   const float* __restrict__ sc, int total4){
  int i = blockIdx.x*256+threadIdx.x;
  if(i<total4){
    int c4=(i&31)*4;
    float4 v = ((const float4*)A)[i];
    ushort4 o;
    o.x = f2bf(silu_f(v.x*sc[c4+0]+sc[128+c4+0]));
    o.y = f2bf(silu_f(v.y*sc[c4+1]+sc[128+c4+1]));
    o.z = f2bf(silu_f(v.z*sc[c4+2]+sc[128+c4+2]));
    o.w = f2bf(silu_f(v.w*sc[c4+3]+sc[128+c4+3]));
    *(ushort4*)&O[(size_t)i*4] = o;
  }
}
// BN+silu, fp32 in-place (mol branch)
__global__ __launch_bounds__(256) void k_bnsilu(float* __restrict__ A, const float* __restrict__ sc, int total4){
  int i = blockIdx.x*256+threadIdx.x;
  if(i<total4){
    int c4=(i&31)*4;
    float4 v = ((const float4*)A)[i];
    v.x = silu_f(v.x*sc[c4+0]+sc[128+c4+0]);
    v.y = silu_f(v.y*sc[c4+1]+sc[128+c4+1]);
    v.z = silu_f(v.z*sc[c4+2]+sc[128+c4+2]);
    v.w = silu_f(v.w*sc[c4+3]+sc[128+c4+3]);
    ((float4*)A)[i] = v;
  }
}

// ---------------- global_add_pool (batch sorted -> range sum per graph) ----------------
__global__ __launch_bounds__(256) void k_pool(const float* __restrict__ h, const int* __restrict__ batch,
                       float* __restrict__ P, int Nn, int G){
  int t = blockIdx.x*256+threadIdx.x;
  int g = t>>5;
  if(g>=G) return;
  int c4=(t&31)*4;
  int lo=0, hi=Nn;
  while(lo<hi){ int m=(lo+hi)>>1; if(batch[m]<g) lo=m+1; else hi=m; }
  int s=lo;
  lo=0; hi=Nn;
  while(lo<hi){ int m=(lo+hi)>>1; if(batch[m]<=g) lo=m+1; else hi=m; }
  int e=lo;
  float ax=0,ay=0,az=0,aw=0;
  for(int r=s;r<e;r++){
    float4 v = *(const float4*)&h[(size_t)r*128+c4];
    ax+=v.x; ay+=v.y; az+=v.z; aw+=v.w;
  }
  float4 o; o.x=ax;o.y=ay;o.z=az;o.w=aw;
  *(float4*)&P[(size_t)g*256+c4] = o;
}

// ---------------- final dot: out[g] = z2[g]@fW3 + fb3 ----------------
__global__ void k_dot(const float* __restrict__ z, const float* __restrict__ w,
                      const float* __restrict__ b, float* __restrict__ out){
  int g = blockIdx.x; int lane = threadIdx.x; // 64
  float p = z[(size_t)g*64+lane]*w[lane];
  #pragma unroll
  for(int off=32;off;off>>=1) p += __shfl_xor(p,off);
  if(lane==0) out[g] = p + b[0];
}

extern "C" void kernel_launch(void* const* d_in, const int* in_sizes, int n_in,
                              void* d_out, int out_size, void* d_ws, size_t ws_size,
                              hipStream_t stream){
  const float* x       =(const float*)d_in[0];
  const float* atom_ens=(const float*)d_in[1];
  const float* mol     =(const float*)d_in[2];
  const int*   eidx    =(const int*)d_in[3];
  const int*   batch   =(const int*)d_in[4];
  const float* W_en=(const float*)d_in[5];  const float* b_en=(const float*)d_in[6];
  const float* gW0=(const float*)d_in[7];   const float* gb0=(const float*)d_in[8];
  const float* gW1=(const float*)d_in[9];   const float* gb1=(const float*)d_in[10];
  const float* gW2=(const float*)d_in[11];  const float* gb2=(const float*)d_in[12];
  const float* bn_gc_g=(const float*)d_in[13]; const float* bn_gc_b=(const float*)d_in[14];
  const float* mW0=(const float*)d_in[15];  const float* mb0=(const float*)d_in[16];
  const float* mW1=(const float*)d_in[17];  const float* mb1=(const float*)d_in[18];
  const float* mW2=(const float*)d_in[19];  const float* mb2=(const float*)d_in[20];
  const float* bn_m_g=(const float*)d_in[21]; const float* bn_m_b=(const float*)d_in[22];
  const float* fW0=(const float*)d_in[23];  const float* fb0=(const float*)d_in[24];
  const float* fW1=(const float*)d_in[25];  const float* fb1=(const float*)d_in[26];
  const float* fW2=(const float*)d_in[27];  const float* fb2=(const float*)d_in[28];
  const float* fW3=(const float*)d_in[29];  const float* fb3=(const float*)d_in[30];

  const int N = in_sizes[1];
  const int E = in_sizes[3]/2;
  const int G = in_sizes[2]/128;
  const int* esrc = eidx;
  const int* edst = eidx+E;

  char* ws=(char*)d_ws;
  size_t o=0;
  float* A=(float*)(ws+o);    o += (size_t)N*128*4;
  float* B=(float*)(ws+o);    o += (size_t)N*128*4;
  unsigned short* Abf=(unsigned short*)(ws+o); o += (size_t)N*128*2;
  float* dinv=(float*)(ws+o); o += (size_t)N*4;
  int* cnt=(int*)(ws+o);      o += (size_t)N*4;
  int* rp=(int*)(ws+o);       o += (size_t)(N+1)*4; o=(o+255)&~(size_t)255;
  int* bs=(int*)(ws+o);       o += 4096;
  float* sums=(float*)(ws+o); o += 1024;
  float* sc=(float*)(ws+o);   o += 1024;
  int* csr=(int*)(ws+o);      o += (size_t)E*4;
  if(o > ws_size) return;

  unsigned short* enbf = (unsigned short*)A;  // N x 64 bf16, dead once gemm0 writes A
  float* P  = B;               // G x 256 (concat buffer; B free after pool input A)
  float* Q  = P + (size_t)G*256;
  float* MB0= Q + (size_t)G*256; // G x 128
  float* MB1= MB0 + (size_t)G*128;
  float* Z2 = MB1 + (size_t)G*128; // G x 64

  dim3 blk256(256);
  int nb = (N+1023)/1024;

  // --- CSR build ---
  hipMemsetAsync(cnt, 0, (size_t)N*4, stream);
  k_hist<<<dim3((E+255)/256), blk256, 0, stream>>>(edst, cnt, E);
  k_dinv<<<dim3((N+255)/256), blk256, 0, stream>>>(cnt, dinv, N);
  k_scan1<<<dim3(nb), blk256, 0, stream>>>(cnt, rp, bs, N);
  k_scan2<<<dim3(1), blk256, 0, stream>>>(bs, nb, rp, N);
  k_scan3<<<dim3((N+255)/256), blk256, 0, stream>>>(rp, bs, N);
  hipMemsetAsync(cnt, 0, (size_t)N*4, stream);
  k_fill<<<dim3((E+255)/256), blk256, 0, stream>>>(esrc, edst, cnt, rp, csr, E);

  // --- en embedding -> enbf (N x 64 bf16, in A's space) ---
  k_en<<<dim3((N+63)/64), blk256, 0, stream>>>(x, W_en, b_en, atom_ens, enbf, N);

  // --- layer 0: prop(en bf16) -> B (64 fp32), @gW0+gb0 -> A (128 fp32), BN, silu->bf16 ---
  k_prop_bf<8><<<dim3((N*8+255)/256), blk256, 0, stream>>>(enbf, B, rp, csr, dinv, N);
  k_gemm<<<dim3((N+63)/64, 2), blk256, 0, stream>>>(B, gW0, gb0, A, (unsigned short*)nullptr, N, 64, 128, 128, 0);
  {
    int nblk=512, rpb=(N+nblk-1)/nblk;
    hipMemsetAsync(sums, 0, 1024, stream);
    k_bnstats<<<dim3(nblk), blk256, 0, stream>>>(A, sums, N, rpb);
    k_bnfinal<<<dim3(1), dim3(128), 0, stream>>>(sums, bn_gc_g, bn_gc_b, sc, N);
    k_bnsilu_bf<<<dim3((N*32+255)/256), blk256, 0, stream>>>(A, Abf, sc, N*32);
  }

  // --- layer 1: prop(Abf) -> B, gemm+silu -> Abf (bf16 only) ---
  k_prop_bf<16><<<dim3((N*16+255)/256), blk256, 0, stream>>>(Abf, B, rp, csr, dinv, N);
  k_gemm<<<dim3((N+63)/64, 2), blk256, 0, stream>>>(B, gW1, gb1, (float*)nullptr, Abf, N, 128, 128, 128, 1);

  // --- layer 2: prop(Abf) -> B, gemm+silu -> A (fp32 for pool) ---
  k_prop_bf<16><<<dim3((N*16+255)/256), blk256, 0, stream>>>(Abf, B, rp, csr, dinv, N);
  k_gemm<<<dim3((N+63)/64, 2), blk256, 0, stream>>>(B, gW2, gb2, A, (unsigned short*)nullptr, N, 128, 128, 128, 1);

  // --- pool into P[:, :128] ---
  k_pool<<<dim3((G*32+255)/256), blk256, 0, stream>>>(A, batch, P, N, G);

  // --- mol branch -> P[:, 128:256] ---
  k_gemm<<<dim3((G+63)/64, 2), blk256, 0, stream>>>(mol, mW0, mb0, MB0, (unsigned short*)nullptr, G, 128, 128, 128, 0);
  {
    int nblk=64, rpb=(G+nblk-1)/nblk;
    hipMemsetAsync(sums, 0, 1024, stream);
    k_bnstats<<<dim3(nblk), blk256, 0, stream>>>(MB0, sums, G, rpb);
    k_bnfinal<<<dim3(1), dim3(128), 0, stream>>>(sums, bn_m_g, bn_m_b, sc, G);
    k_bnsilu<<<dim3((G*32+255)/256), blk256, 0, stream>>>(MB0, sc, G*32);
  }
  k_gemm<<<dim3((G+63)/64, 2), blk256, 0, stream>>>(MB0, mW1, mb1, MB1, (unsigned short*)nullptr, G, 128, 128, 128, 1);
  k_gemm<<<dim3((G+63)/64, 2), blk256, 0, stream>>>(MB1, mW2, mb2, P+128, (unsigned short*)nullptr, G, 128, 128, 256, 1);

  // --- fused head ---
  k_gemm<<<dim3((G+63)/64, 4), blk256, 0, stream>>>(P, fW0, fb0, Q, (unsigned short*)nullptr, G, 256, 256, 256, 1);
  k_gemm<<<dim3((G+63)/64, 4), blk256, 0, stream>>>(Q, fW1, fb1, P, (unsigned short*)nullptr, G, 256, 256, 256, 1);
  k_gemm<<<dim3((G+63)/64, 1), blk256, 0, stream>>>(P, fW2, fb2, Z2, (unsigned short*)nullptr, G, 256, 64, 64, 1);
  k_dot<<<dim3(G), dim3(64), 0, stream>>>(Z2, fW3, fb3, (float*)d_out);
}